// Round 7
// baseline (107.537 us; speedup 1.0000x reference)
//
#include <hip/hip_runtime.h>
#include <hip/hip_bf16.h>
#include <math.h>

#define BSZ   128
#define NP    16
#define NC    21
#define NH    256
#define HOUT  16
#define NFLAT 5376     // K (permuted layout k' = p*336 + c*16 + wo)

typedef __attribute__((ext_vector_type(4))) float f32x4;
typedef __attribute__((ext_vector_type(8))) short bf16x8;

__device__ __forceinline__ ushort f2bf(float v) {
    __hip_bfloat16 h = __float2bfloat16(v);
    return *reinterpret_cast<ushort*>(&h);
}

// tanh(0.01*ln(s)) = (s^0.02 - 1)/(s^0.02 + 1)
__device__ __forceinline__ float hist_act(float s) {
    float a = __expf(0.02f * __logf(fmaxf(s, 1e-10f)));
    return (a - 1.f) * __builtin_amdgcn_rcpf(a + 1.f);
}

// tanh(x) = 1 - 2/(e^{2x}+1)
__device__ __forceinline__ float fast_tanh(float v) {
    float e = __expf(2.f * v);
    return 1.f - 2.f * __builtin_amdgcn_rcpf(e + 1.f);
}

// Release-arrive + (optional) acquire-spin grid barrier. All N blocks must
// arrive; only waiters spin. Requires all blocks resident (256 blocks, 1/CU,
// 54KB LDS => 2 blocks/CU capacity -> guaranteed).
__device__ __forceinline__ void grid_arrive_wait(uint* cnt, uint expected, bool wait) {
    __syncthreads();
    if (threadIdx.x == 0) {
        __hip_atomic_fetch_add(cnt, 1u, __ATOMIC_RELEASE, __HIP_MEMORY_SCOPE_AGENT);
        if (wait) {
            while (__hip_atomic_load(cnt, __ATOMIC_ACQUIRE, __HIP_MEMORY_SCOPE_AGENT) < expected)
                __builtin_amdgcn_s_sleep(2);
        }
    }
    __syncthreads();
}

#define SMEM_BYTES 55296

__global__ __launch_bounds__(512) void k_all(
    const float* __restrict__ sim,     // [128][16][64][64]
    const float* __restrict__ W,       // [5376][256]
    ushort* __restrict__ x,            // [2048][5376] bf16
    ushort* __restrict__ Wt,           // [256][5376] bf16
    float* __restrict__ part,          // [4][2048][256]
    const float* __restrict__ b_flat,
    const float* __restrict__ f_add,
    const float* __restrict__ W_attn,
    const float* __restrict__ b_attn,
    const float* __restrict__ W_fadd,
    const float* __restrict__ b_fadd,
    const float* __restrict__ W_d1,
    const float* __restrict__ b_d1,
    const float* __restrict__ W_d2,
    const float* __restrict__ b_d2,
    const float* __restrict__ wfeat,
    float* __restrict__ out,
    uint* __restrict__ cnt)            // [2] zeroed per launch
{
    __shared__ __align__(16) char smem[SMEM_BYTES];
    const int bid = blockIdx.x;
    const int tid = threadIdx.x;
    const int tloc = tid >> 8;         // 0/1: which 256-thread group
    const int tid256 = tid & 255;

    // ================= PHASE A: W-prep + RBF =================
    // --- prep: Wt[n][k'] = bf16(W[k][n]), 336 units, 2 per block for bid<168
    if (bid < 168) {
        ushort* ldsT = (ushort*)(smem) + tloc * (64 * 72);   // 2x9216B
        int pb = bid * 2 + tloc;                              // 0..335
        int kb = pb % 84, nb = pb / 84;
        int k0 = kb * 64, n0 = nb * 64;
        int nl = tid256 & 63, kq = tid256 >> 6;
#pragma unroll
        for (int i = 0; i < 16; ++i) {
            int kl = i * 4 + kq;
            ldsT[nl * 72 + kl] = f2bf(W[(size_t)(k0 + kl) * NH + n0 + nl]);
        }
        __syncthreads();
        int n = tid256 >> 2, q = tid256 & 3;
        int k = k0 + q * 16;
        int c = k >> 8, p = (k >> 4) & 15;
        ushort* dst = Wt + (size_t)(n0 + n) * NFLAT + p * 336 + c * 16;
        const ushort* srow = &ldsT[n * 72 + q * 16];
#pragma unroll
        for (int i = 0; i < 8; ++i) {
            ushort2 v; v.x = srow[2 * i]; v.y = srow[2 * i + 1];
            ((ushort2*)dst)[i] = v;
        }
    }
    __syncthreads();

    // --- RBF: 8 tiles per block, 2 concurrent (512 thr)
    {
        float* simLds = (float*)smem;                          // 2 x 4096 f32 = 32KB
        ushort* stage = (ushort*)(smem + 32768);               // 2 x 5376 ushort = 21KB
        float* stile = simLds + tloc * 4096;
        ushort* mystage = stage + tloc * 5376;

        for (int round = 0; round < 4; ++round) {
            int bp = bid * 8 + round * 2 + tloc;               // 0..2047
            int b = bp >> 4, p = bp & 15;
            const float* src = sim + (size_t)bp * 4096;
#pragma unroll
            for (int i = 0; i < 16; ++i)
                stile[i * 256 + tid256] = src[i * 256 + tid256];
            __syncthreads();

            int wo = tid256 & 15, ho = tid256 >> 4;
            float f[16], g[16];
            float sum0 = 0.f;
#pragma unroll
            for (int i = 0; i < 4; ++i)
#pragma unroll
                for (int j = 0; j < 4; ++j) {
                    float e = stile[(ho * 4 + i) * 64 + wo * 4 + j];
                    int k2 = i * 4 + j;
                    float d0 = e - 1.0f;
                    sum0 += __expf(-50.f * d0 * d0);
                    float d1 = e - 0.95f;
                    f[k2] = __expf(-50.f * d1 * d1);
                    g[k2] = __expf(-10.f * d1 - 0.5f);
                }

            mystage[ho * 336 + wo] = f2bf(hist_act(sum0));
#pragma unroll
            for (int c = 1; c < 21; ++c) {
                float sv = 0.f;
#pragma unroll
                for (int k2 = 0; k2 < 16; ++k2) sv += f[k2];
                mystage[ho * 336 + c * 16 + wo] = f2bf(hist_act(sv));
                if (c < 20) {
#pragma unroll
                    for (int k2 = 0; k2 < 16; ++k2) { f[k2] *= g[k2]; g[k2] *= 0.36787944117f; }
                }
            }
            __syncthreads();

            // coalesced write-out: 2688 dwords per tile
            const uint* ssrc = (const uint*)mystage;
            char* xb = (char*)x;
#pragma unroll
            for (int it = 0; it < 11; ++it) {
                int i = it * 256 + tid256;
                if (i < 2688) {
                    int row = i / 168;
                    int jc = i - row * 168;
                    *(uint*)(xb + ((size_t)(b * 16 + row) * NFLAT + p * 336) * 2 + jc * 4) = ssrc[i];
                }
            }
            __syncthreads();
        }
    }

    // ================= barrier A -> B =================
    grid_arrive_wait(cnt, 256, true);

    // ================= PHASE B: MFMA GEMM (split-K) =================
    {
        char* lds = smem;                                      // 2 x 24576
        int bm = bid >> 3, bn = (bid >> 2) & 1, sk = bid & 3;
        int t = tid;
        int l = t & 63, w = t >> 6;
        int wr = w >> 1, wc = w & 1;
        int row0 = bm * 64, col0 = bn * 128;
        int kbase = sk * 1344;

        int ar = t >> 3, s8 = t & 7;
        int br1 = ar + 64;
        int wA  = ar * 128 + ((s8 ^ (ar & 7)) << 4);
        int wB0 = 8192 + ar * 128 + ((s8 ^ (ar & 7)) << 4);
        int wB1 = 8192 + br1 * 128 + ((s8 ^ (br1 & 7)) << 4);

        const ushort* gA  = x  + (size_t)(row0 + ar) * NFLAT + kbase + s8 * 8;
        const ushort* gB0 = Wt + (size_t)(col0 + ar) * NFLAT + kbase + s8 * 8;
        const ushort* gB1 = Wt + (size_t)(col0 + br1) * NFLAT + kbase + s8 * 8;

        int arow = wr * 16 + (l & 15);
        int lk = l >> 4;
        int brow0 = wc * 64 + (l & 15);

        f32x4 acc[4];
#pragma unroll
        for (int n = 0; n < 4; ++n) acc[n] = (f32x4){0.f, 0.f, 0.f, 0.f};

        uint4 ra = *(const uint4*)gA;
        uint4 rb0 = *(const uint4*)gB0;
        uint4 rb1 = *(const uint4*)gB1;
        *(uint4*)(&lds[wA])  = ra;
        *(uint4*)(&lds[wB0]) = rb0;
        *(uint4*)(&lds[wB1]) = rb1;
        __syncthreads();

#pragma unroll 1
        for (int tt = 0; tt < 21; ++tt) {
            if (tt < 20) {
                ra  = *(const uint4*)(gA  + (tt + 1) * 64);
                rb0 = *(const uint4*)(gB0 + (tt + 1) * 64);
                rb1 = *(const uint4*)(gB1 + (tt + 1) * 64);
            }
            const char* As = lds + (tt & 1) * 24576;
            const char* Bs = As + 8192;
#pragma unroll
            for (int ks = 0; ks < 2; ++ks) {
                int slot = (ks << 2) | lk;
                bf16x8 a = *(const bf16x8*)(As + arow * 128 + ((slot ^ (arow & 7)) << 4));
#pragma unroll
                for (int n = 0; n < 4; ++n) {
                    int brow = brow0 + n * 16;
                    bf16x8 bb = *(const bf16x8*)(Bs + brow * 128 + ((slot ^ (brow & 7)) << 4));
                    acc[n] = __builtin_amdgcn_mfma_f32_16x16x32_bf16(a, bb, acc[n], 0, 0, 0);
                }
            }
            if (tt < 20) {
                char* nb = lds + ((tt + 1) & 1) * 24576;
                *(uint4*)(nb + wA)  = ra;
                *(uint4*)(nb + wB0) = rb0;
                *(uint4*)(nb + wB1) = rb1;
            }
            __syncthreads();
        }

        float* pp = part + (size_t)sk * 2048 * 256;
        int crow = row0 + wr * 16 + lk * 4;
#pragma unroll
        for (int n = 0; n < 4; ++n) {
            int ccol = col0 + wc * 64 + n * 16 + (l & 15);
#pragma unroll
            for (int j = 0; j < 4; ++j)
                pp[(size_t)(crow + j) * 256 + ccol] = acc[n][j];
        }
    }

    // ================= barrier B -> C =================
    grid_arrive_wait(cnt + 1, 256, bid < 128);
    if (bid >= 128) return;

    // ================= PHASE C: head (blocks 0..127) =================
    {
        const int b = bid;
        float* sh1   = (float*)smem;           // 4096 f32 = 16KB
        float* slog  = sh1 + 4096;             // 16
        float* scomb = slog + 16;              // 256
        float* scpart= scomb + 256;            // 512
        float* r01   = scpart + 512;           // 8

#pragma unroll
        for (int i = 0; i < 8; ++i) {
            int idx = i * 512 + tid;
            int row = idx >> 8, col = idx & 255;
            size_t prow = (size_t)(b * 16 + row) * 256 + col;
            float v = b_flat[col] + part[prow] + part[524288 + prow]
                    + part[2 * 524288 + prow] + part[3 * 524288 + prow];
            sh1[idx] = fast_tanh(v);
        }
        __syncthreads();

        if (tid < 256) {
            int ho = tid >> 4, j = tid & 15;
            float s = 0.f;
#pragma unroll
            for (int t2 = 0; t2 < 16; ++t2)
                s += sh1[ho * 256 + j + t2 * 16] * W_attn[j + t2 * 16];
            s += __shfl_xor(s, 1); s += __shfl_xor(s, 2);
            s += __shfl_xor(s, 4); s += __shfl_xor(s, 8);
            if (j == 0) slog[ho] = s + b_attn[0];
        }
        __syncthreads();

        if (tid < 256) {
            float attnv[16];
            float mx = -1e30f;
#pragma unroll
            for (int t2 = 0; t2 < 16; ++t2) mx = fmaxf(mx, slog[t2]);
            float sum = 0.f;
#pragma unroll
            for (int t2 = 0; t2 < 16; ++t2) { attnv[t2] = __expf(slog[t2] - mx); sum += attnv[t2]; }
            float inv = __builtin_amdgcn_rcpf(sum);

            float lc = 0.f;
#pragma unroll
            for (int t2 = 0; t2 < 16; ++t2) lc += attnv[t2] * inv * sh1[t2 * 256 + tid];
            lc = fast_tanh(lc);

            float fp = b_fadd[tid];
#pragma unroll
            for (int k = 0; k < 17; ++k) fp += f_add[b * 17 + k] * W_fadd[k * 256 + tid];
            fp = fast_tanh(fp);

            float sg = __builtin_amdgcn_rcpf(1.f + __expf(-wfeat[0]));
            scomb[tid] = (1.f - sg) * fp + sg * lc;
        }
        __syncthreads();

        // d1 matvec split over 512 threads (2 k-halves)
        {
            int n = tid & 255, half = tid >> 8;
            float sc = 0.f;
            int k0 = half * 128;
#pragma unroll 8
            for (int k = 0; k < 128; ++k) sc += scomb[k0 + k] * W_d1[(k0 + k) * 256 + n];
            scpart[half * 256 + n] = sc;
        }
        __syncthreads();

        if (tid < 256) {
            float sc = fast_tanh(scpart[tid] + scpart[256 + tid] + b_d1[tid]);
            float p0 = sc * W_d2[tid * 2 + 0];
            float p1 = sc * W_d2[tid * 2 + 1];
#pragma unroll
            for (int off = 1; off < 64; off <<= 1) {
                p0 += __shfl_xor(p0, off);
                p1 += __shfl_xor(p1, off);
            }
            if ((tid & 63) == 0) { r01[tid >> 6] = p0; r01[4 + (tid >> 6)] = p1; }
        }
        __syncthreads();

        if (tid == 0) {
            float o0 = r01[0] + r01[1] + r01[2] + r01[3] + b_d2[0];
            float o1 = r01[4] + r01[5] + r01[6] + r01[7] + b_d2[1];
            float mx = fmaxf(o0, o1);
            float lse = mx + __logf(__expf(o0 - mx) + __expf(o1 - mx));
            out[b * 2 + 0] = o0 - lse;
            out[b * 2 + 1] = o1 - lse;
            out[256 + b * 2 + 0] = o0;
            out[256 + b * 2 + 1] = o1;
        }
    }
}

// ---------------------------------------------------------------------------
extern "C" void kernel_launch(void* const* d_in, const int* in_sizes, int n_in,
                              void* d_out, int out_size, void* d_ws, size_t ws_size,
                              hipStream_t stream) {
    const float* sim    = (const float*)d_in[0];
    const float* f_add  = (const float*)d_in[1];
    const float* W_flat = (const float*)d_in[2];
    const float* b_flat = (const float*)d_in[3];
    const float* W_attn = (const float*)d_in[4];
    const float* b_attn = (const float*)d_in[5];
    const float* W_fadd = (const float*)d_in[6];
    const float* b_fadd = (const float*)d_in[7];
    const float* W_d1   = (const float*)d_in[8];
    const float* b_d1   = (const float*)d_in[9];
    const float* W_d2   = (const float*)d_in[10];
    const float* b_d2   = (const float*)d_in[11];
    const float* wfeat  = (const float*)d_in[12];
    float* out = (float*)d_out;

    ushort* x  = (ushort*)d_ws;                        // [2048][5376] bf16 (22MB)
    ushort* Wt = x + (size_t)2048 * NFLAT;             // [256][5376] bf16 (2.75MB)
    float* part = (float*)(Wt + (size_t)256 * NFLAT);  // [4][2048][256] f32 (8MB)
    uint* cnt = (uint*)((char*)d_ws + (36u << 20));    // 2 counters @36MB (ws>=46MB, round-1 proven)

    hipMemsetAsync(cnt, 0, 2 * sizeof(uint), stream);
    hipLaunchKernelGGL(k_all, dim3(256), dim3(512), 0, stream,
                       sim, W_flat, x, Wt, part,
                       b_flat, f_add, W_attn, b_attn, W_fadd, b_fadd,
                       W_d1, b_d1, W_d2, b_d2, wfeat, out, cnt);
}

// Round 8
// 70.787 us; speedup vs baseline: 1.5191x; 1.5191x over previous
//
#include <hip/hip_runtime.h>
#include <hip/hip_bf16.h>
#include <math.h>

#define BSZ   128
#define NP    16
#define NC    21
#define NH    256
#define HOUT  16
#define NFLAT 5376     // K (permuted layout k' = p*336 + c*16 + wo)

typedef __attribute__((ext_vector_type(4))) float f32x4;
typedef __attribute__((ext_vector_type(2))) float f32x2;
typedef __attribute__((ext_vector_type(8))) short bf16x8;

__device__ __forceinline__ ushort f2bf(float v) {
    __hip_bfloat16 h = __float2bfloat16(v);
    return *reinterpret_cast<ushort*>(&h);
}

// tanh(0.01*ln(s)) via odd poly: u=0.01*ln(s) in [-0.23, 0.03]; tanh(u)=u-u^3/3+2u^5/15
__device__ __forceinline__ float hist_act(float s) {
    float u = 0.01f * __logf(fmaxf(s, 1e-10f));
    float u2 = u * u;
    return u * (1.f + u2 * (-0.33333333f + 0.13333333f * u2));
}

// tanh(x) = 1 - 2/(e^{2x}+1)
__device__ __forceinline__ float fast_tanh(float v) {
    float e = __expf(2.f * v);
    return 1.f - 2.f * __builtin_amdgcn_rcpf(e + 1.f);
}

// ---------------------------------------------------------------------------
// Kernel 1: blocks 0..2047 RBF (one (b,p) tile), blocks 2048..2383 W-prep.
// x layout: [2048][5376] bf16, k' = p*336 + c*16 + wo
// ---------------------------------------------------------------------------
__global__ __launch_bounds__(256) void k_pre(const float* __restrict__ sim,
                                             ushort* __restrict__ x,
                                             const float* __restrict__ W,
                                             ushort* __restrict__ Wt) {
    int tid = threadIdx.x;

    if (blockIdx.x >= 2048) {
        // ---- prep: Wt[n][k'] = bf16(W[k][n]) ----
        __shared__ ushort ldsT[64][72];
        int pb = blockIdx.x - 2048;          // 0..335
        int kb = pb % 84, nb = pb / 84;
        int k0 = kb * 64, n0 = nb * 64;
        int nl = tid & 63, kq = tid >> 6;
#pragma unroll
        for (int i = 0; i < 16; ++i) {
            int kl = i * 4 + kq;
            ldsT[nl][kl] = f2bf(W[(size_t)(k0 + kl) * NH + n0 + nl]);
        }
        __syncthreads();
        int n = tid >> 2, q = tid & 3;
        int k = k0 + q * 16;
        int c = k >> 8, p = (k >> 4) & 15;
        ushort* dst = Wt + (size_t)(n0 + n) * NFLAT + p * 336 + c * 16;
        const ushort* srow = &ldsT[n][q * 16];
#pragma unroll
        for (int i = 0; i < 8; ++i) {
            ushort2 v; v.x = srow[2 * i]; v.y = srow[2 * i + 1];
            ((ushort2*)dst)[i] = v;
        }
        return;
    }

    // ---- RBF ----
    int bp = blockIdx.x, b = bp >> 4, p = bp & 15;
    __shared__ float s[4096];
    __shared__ ushort stage[16 * 336];
    const float4* src4 = (const float4*)(sim + (size_t)bp * 4096);
    float4* s4 = (float4*)s;
#pragma unroll
    for (int i = 0; i < 4; ++i) s4[i * 256 + tid] = src4[i * 256 + tid];
    __syncthreads();

    int wo = tid & 15, ho = tid >> 4;
    f32x2 f[8], g[8];
    float sum0 = 0.f;
#pragma unroll
    for (int i = 0; i < 4; ++i)
#pragma unroll
        for (int j = 0; j < 4; ++j) {
            float e = s[(ho * 4 + i) * 64 + wo * 4 + j];
            int k2 = i * 4 + j;
            float d0 = e - 1.0f;
            sum0 += __expf(-50.f * d0 * d0);
            float d1 = e - 0.95f;
            float fv = __expf(-50.f * d1 * d1);
            float gv = __expf(-10.f * d1 - 0.5f);
            if (k2 & 1) { f[k2 >> 1].y = fv; g[k2 >> 1].y = gv; }
            else        { f[k2 >> 1].x = fv; g[k2 >> 1].x = gv; }
        }

    stage[ho * 336 + wo] = f2bf(hist_act(sum0));
    const f32x2 E2 = {0.36787944117f, 0.36787944117f};
#pragma unroll
    for (int c = 1; c < 21; ++c) {
        f32x2 acc = {0.f, 0.f};
#pragma unroll
        for (int k2 = 0; k2 < 8; ++k2) acc += f[k2];
        stage[ho * 336 + c * 16 + wo] = f2bf(hist_act(acc.x + acc.y));
        if (c < 20) {
#pragma unroll
            for (int k2 = 0; k2 < 8; ++k2) { f[k2] *= g[k2]; g[k2] *= E2; }
        }
    }
    __syncthreads();

    // cooperative coalesced write-out: 2688 dwords
    const uint* ssrc = (const uint*)stage;
    char* xb = (char*)x;
#pragma unroll
    for (int it = 0; it < 11; ++it) {
        int i = it * 256 + tid;
        if (i < 2688) {
            int row = i / 168;
            int jc = i - row * 168;
            *(uint*)(xb + ((size_t)(b * 16 + row) * NFLAT + p * 336) * 2 + jc * 4) = ssrc[i];
        }
    }
}

// ---------------------------------------------------------------------------
// Kernel 2: MFMA GEMM (split-K) + fused head.
// 256 blocks x 512 thr. GEMM: bid -> (bm = bid>>3, bn = (bid>>2)&1, sk = bid&3).
// After storing partials, block arrives at cnt[bm]; blocks 0..127 then wait
// for cnt[bid>>2]==8 (2 bn x 4 sk producers) and run the head for b=bid.
// ---------------------------------------------------------------------------
__global__ __launch_bounds__(512) void k_gemmhead(
    const ushort* __restrict__ A,      // x
    const ushort* __restrict__ Bt,     // Wt
    float* __restrict__ part,          // [4][2048][256]
    const float* __restrict__ b_flat,
    const float* __restrict__ f_add,
    const float* __restrict__ W_attn,
    const float* __restrict__ b_attn,
    const float* __restrict__ W_fadd,
    const float* __restrict__ b_fadd,
    const float* __restrict__ W_d1,
    const float* __restrict__ b_d1,
    const float* __restrict__ W_d2,
    const float* __restrict__ b_d2,
    const float* __restrict__ wfeat,
    float* __restrict__ out,
    uint* __restrict__ cnt)            // [32] zeroed per launch
{
    __shared__ __align__(16) char smem[49152];   // GEMM dbuf 2x24576; head reuses
    const int bid = blockIdx.x;
    const int tid = threadIdx.x;

    // ================= GEMM =================
    {
        char* lds = smem;
        int bm = bid >> 3, bn = (bid >> 2) & 1, sk = bid & 3;
        int l = tid & 63, w = tid >> 6;
        int wr = w >> 1, wc = w & 1;
        int row0 = bm * 64, col0 = bn * 128;
        int kbase = sk * 1344;

        int ar = tid >> 3, s8 = tid & 7;
        int br1 = ar + 64;
        int wA  = ar * 128 + ((s8 ^ (ar & 7)) << 4);
        int wB0 = 8192 + ar * 128 + ((s8 ^ (ar & 7)) << 4);
        int wB1 = 8192 + br1 * 128 + ((s8 ^ (br1 & 7)) << 4);

        const ushort* gA  = A  + (size_t)(row0 + ar) * NFLAT + kbase + s8 * 8;
        const ushort* gB0 = Bt + (size_t)(col0 + ar) * NFLAT + kbase + s8 * 8;
        const ushort* gB1 = Bt + (size_t)(col0 + br1) * NFLAT + kbase + s8 * 8;

        int arow = wr * 16 + (l & 15);
        int lk = l >> 4;
        int brow0 = wc * 64 + (l & 15);

        f32x4 acc[4];
#pragma unroll
        for (int n = 0; n < 4; ++n) acc[n] = (f32x4){0.f, 0.f, 0.f, 0.f};

        uint4 ra = *(const uint4*)gA;
        uint4 rb0 = *(const uint4*)gB0;
        uint4 rb1 = *(const uint4*)gB1;
        *(uint4*)(&lds[wA])  = ra;
        *(uint4*)(&lds[wB0]) = rb0;
        *(uint4*)(&lds[wB1]) = rb1;
        __syncthreads();

#pragma unroll 1
        for (int tt = 0; tt < 21; ++tt) {
            if (tt < 20) {
                ra  = *(const uint4*)(gA  + (tt + 1) * 64);
                rb0 = *(const uint4*)(gB0 + (tt + 1) * 64);
                rb1 = *(const uint4*)(gB1 + (tt + 1) * 64);
            }
            const char* As = lds + (tt & 1) * 24576;
            const char* Bs = As + 8192;
#pragma unroll
            for (int ks = 0; ks < 2; ++ks) {
                int slot = (ks << 2) | lk;
                bf16x8 a = *(const bf16x8*)(As + arow * 128 + ((slot ^ (arow & 7)) << 4));
#pragma unroll
                for (int n = 0; n < 4; ++n) {
                    int brow = brow0 + n * 16;
                    bf16x8 bb = *(const bf16x8*)(Bs + brow * 128 + ((slot ^ (brow & 7)) << 4));
                    acc[n] = __builtin_amdgcn_mfma_f32_16x16x32_bf16(a, bb, acc[n], 0, 0, 0);
                }
            }
            if (tt < 20) {
                char* nb = lds + ((tt + 1) & 1) * 24576;
                *(uint4*)(nb + wA)  = ra;
                *(uint4*)(nb + wB0) = rb0;
                *(uint4*)(nb + wB1) = rb1;
            }
            __syncthreads();
        }

        float* pp = part + (size_t)sk * 2048 * 256;
        int crow = row0 + wr * 16 + lk * 4;
#pragma unroll
        for (int n = 0; n < 4; ++n) {
            int ccol = col0 + wc * 64 + n * 16 + (l & 15);
#pragma unroll
            for (int j = 0; j < 4; ++j)
                pp[(size_t)(crow + j) * 256 + ccol] = acc[n][j];
        }

        // arrive: all this block's stores have drained (syncthreads waits vmcnt)
        __syncthreads();
        if (tid == 0)
            __hip_atomic_fetch_add(&cnt[bm], 1u, __ATOMIC_RELEASE, __HIP_MEMORY_SCOPE_AGENT);
    }

    if (bid >= 128) return;

    // wait for this b's 8 producers (bm = bid>>2)
    if (tid == 0) {
        while (__hip_atomic_load(&cnt[bid >> 2], __ATOMIC_ACQUIRE, __HIP_MEMORY_SCOPE_AGENT) < 8u)
            __builtin_amdgcn_s_sleep(2);
    }
    __syncthreads();

    // ================= HEAD (b = bid) =================
    {
        const int b = bid;
        float* sh1   = (float*)smem;           // 4096 f32
        float* slog  = sh1 + 4096;             // 16
        float* scomb = slog + 16;              // 256
        float* scpart= scomb + 256;            // 512
        float* r01   = scpart + 512;           // 8

#pragma unroll
        for (int i = 0; i < 8; ++i) {
            int idx = i * 512 + tid;
            int row = idx >> 8, col = idx & 255;
            size_t prow = (size_t)(b * 16 + row) * 256 + col;
            float v = b_flat[col] + part[prow] + part[524288 + prow]
                    + part[2 * 524288 + prow] + part[3 * 524288 + prow];
            sh1[idx] = fast_tanh(v);
        }
        __syncthreads();

        if (tid < 256) {
            int ho = tid >> 4, j = tid & 15;
            float sv = 0.f;
#pragma unroll
            for (int t2 = 0; t2 < 16; ++t2)
                sv += sh1[ho * 256 + j + t2 * 16] * W_attn[j + t2 * 16];
            sv += __shfl_xor(sv, 1); sv += __shfl_xor(sv, 2);
            sv += __shfl_xor(sv, 4); sv += __shfl_xor(sv, 8);
            if (j == 0) slog[ho] = sv + b_attn[0];
        }
        __syncthreads();

        if (tid < 256) {
            float attnv[16];
            float mx = -1e30f;
#pragma unroll
            for (int t2 = 0; t2 < 16; ++t2) mx = fmaxf(mx, slog[t2]);
            float sum = 0.f;
#pragma unroll
            for (int t2 = 0; t2 < 16; ++t2) { attnv[t2] = __expf(slog[t2] - mx); sum += attnv[t2]; }
            float inv = __builtin_amdgcn_rcpf(sum);

            float lc = 0.f;
#pragma unroll
            for (int t2 = 0; t2 < 16; ++t2) lc += attnv[t2] * inv * sh1[t2 * 256 + tid];
            lc = fast_tanh(lc);

            float fp = b_fadd[tid];
#pragma unroll
            for (int k = 0; k < 17; ++k) fp += f_add[b * 17 + k] * W_fadd[k * 256 + tid];
            fp = fast_tanh(fp);

            float sg = __builtin_amdgcn_rcpf(1.f + __expf(-wfeat[0]));
            scomb[tid] = (1.f - sg) * fp + sg * lc;
        }
        __syncthreads();

        {
            int n = tid & 255, half = tid >> 8;
            float sc = 0.f;
            int k0 = half * 128;
#pragma unroll 8
            for (int k = 0; k < 128; ++k) sc += scomb[k0 + k] * W_d1[(k0 + k) * 256 + n];
            scpart[half * 256 + n] = sc;
        }
        __syncthreads();

        if (tid < 256) {
            float sc = fast_tanh(scpart[tid] + scpart[256 + tid] + b_d1[tid]);
            float p0 = sc * W_d2[tid * 2 + 0];
            float p1 = sc * W_d2[tid * 2 + 1];
#pragma unroll
            for (int off = 1; off < 64; off <<= 1) {
                p0 += __shfl_xor(p0, off);
                p1 += __shfl_xor(p1, off);
            }
            if ((tid & 63) == 0) { r01[tid >> 6] = p0; r01[4 + (tid >> 6)] = p1; }
        }
        __syncthreads();

        if (tid == 0) {
            float o0 = r01[0] + r01[1] + r01[2] + r01[3] + b_d2[0];
            float o1 = r01[4] + r01[5] + r01[6] + r01[7] + b_d2[1];
            float mx = fmaxf(o0, o1);
            float lse = mx + __logf(__expf(o0 - mx) + __expf(o1 - mx));
            out[b * 2 + 0] = o0 - lse;
            out[b * 2 + 1] = o1 - lse;
            out[256 + b * 2 + 0] = o0;
            out[256 + b * 2 + 1] = o1;
        }
    }
}

// ---------------------------------------------------------------------------
extern "C" void kernel_launch(void* const* d_in, const int* in_sizes, int n_in,
                              void* d_out, int out_size, void* d_ws, size_t ws_size,
                              hipStream_t stream) {
    const float* sim    = (const float*)d_in[0];
    const float* f_add  = (const float*)d_in[1];
    const float* W_flat = (const float*)d_in[2];
    const float* b_flat = (const float*)d_in[3];
    const float* W_attn = (const float*)d_in[4];
    const float* b_attn = (const float*)d_in[5];
    const float* W_fadd = (const float*)d_in[6];
    const float* b_fadd = (const float*)d_in[7];
    const float* W_d1   = (const float*)d_in[8];
    const float* b_d1   = (const float*)d_in[9];
    const float* W_d2   = (const float*)d_in[10];
    const float* b_d2   = (const float*)d_in[11];
    const float* wfeat  = (const float*)d_in[12];
    float* out = (float*)d_out;

    ushort* x  = (ushort*)d_ws;                        // [2048][5376] bf16 (22MB)
    ushort* Wt = x + (size_t)2048 * NFLAT;             // [256][5376] bf16 (2.75MB)
    float* part = (float*)(Wt + (size_t)256 * NFLAT);  // [4][2048][256] f32 (8MB)
    uint* cnt = (uint*)((char*)d_ws + (36u << 20));    // 32 counters @36MB

    hipMemsetAsync(cnt, 0, 32 * sizeof(uint), stream);
    hipLaunchKernelGGL(k_pre, dim3(2048 + 336), dim3(256), 0, stream, sim, x, W_flat, Wt);
    hipLaunchKernelGGL(k_gemmhead, dim3(256), dim3(512), 0, stream,
                       x, Wt, part,
                       b_flat, f_add, W_attn, b_attn, W_fadd, b_fadd,
                       W_d1, b_d1, W_d2, b_d2, wfeat, out, cnt);
}